// Round 1
// baseline (278.694 us; speedup 1.0000x reference)
//
#include <hip/hip_runtime.h>

// Problem constants
#define LSEQ 512      // L
#define DDIM 256      // D
#define PDIM 128      // PAIR_DIM
#define BLROWS 1024   // B * L
#define ROWS 8        // h-rows per block in projection kernel

// Kernel 1: P1[bl][p] = dot(h[bl,:], W[p, 0:256])
//           P2b[bl][p] = dot(h[bl,:], W[p, 256:512]) + bias[p]
// 128 blocks x 256 threads; threads 0..127 -> P1, 128..255 -> P2b.
__global__ __launch_bounds__(256) void pair_proj(
    const float* __restrict__ h, const float* __restrict__ W,
    const float* __restrict__ bias, float* __restrict__ P1,
    float* __restrict__ P2b)
{
    __shared__ float4 hsh[ROWS * (DDIM / 4)];  // 8 rows x 64 float4 = 8 KB

    const int t   = threadIdx.x;
    const int bl0 = blockIdx.x * ROWS;

    // Cooperative load of 8 h-rows (512 float4) into LDS, coalesced.
    const float4* h4 = (const float4*)h + (size_t)bl0 * (DDIM / 4);
    hsh[t]       = h4[t];
    hsh[t + 256] = h4[t + 256];
    __syncthreads();

    const int p    = t & (PDIM - 1);
    const int half = t >> 7;  // 0 -> W1 (P1), 1 -> W2 (P2b)

    const float4* w4 = (const float4*)(W + (size_t)p * (2 * DDIM) + half * DDIM);

    float acc[ROWS];
#pragma unroll
    for (int r = 0; r < ROWS; ++r) acc[r] = 0.f;

#pragma unroll 8
    for (int d4 = 0; d4 < DDIM / 4; ++d4) {
        const float4 w = w4[d4];
#pragma unroll
        for (int r = 0; r < ROWS; ++r) {
            const float4 hh = hsh[r * (DDIM / 4) + d4];  // wave-uniform -> LDS broadcast
            acc[r] = fmaf(w.x, hh.x, acc[r]);
            acc[r] = fmaf(w.y, hh.y, acc[r]);
            acc[r] = fmaf(w.z, hh.z, acc[r]);
            acc[r] = fmaf(w.w, hh.w, acc[r]);
        }
    }

    float* dst      = half ? P2b : P1;
    const float bb  = half ? bias[p] : 0.f;
#pragma unroll
    for (int r = 0; r < ROWS; ++r)
        dst[(size_t)(bl0 + r) * PDIM + p] = acc[r] + bb;
}

// Kernel 2: out[b,i,j,p] = P1[b,i,p] + P2b[b,j,p]
// grid (1024, 2): block = one (b,i) and one half of the j range.
// thread: p4 = t&31 (float4 along p), jl = t>>5 (8 j's per iteration).
// Wave stores are 64 consecutive float4 = 1 KB contiguous.
__global__ __launch_bounds__(256) void bcast_add(
    const float4* __restrict__ P1, const float4* __restrict__ P2b,
    float4* __restrict__ out)
{
    const int t  = threadIdx.x;
    const int p4 = t & 31;
    const int jl = t >> 5;               // 0..7
    const int bi = blockIdx.x;           // b*512 + i
    const int b  = bi >> 9;
    const int j0 = blockIdx.y * 256 + jl;

    const float4 a = P1[(size_t)bi * 32 + p4];  // invariant across the loop

    const float4* src = P2b + ((size_t)(b * LSEQ + j0)) * 32 + p4;
    float4*       dst = out + ((size_t)bi * LSEQ + j0) * 32 + p4;

#pragma unroll 8
    for (int it = 0; it < 32; ++it) {           // j advances by 8 each iter
        float4 v = src[(size_t)it * 256];       // 8 j * 32 float4
        v.x += a.x; v.y += a.y; v.z += a.z; v.w += a.w;
        dst[(size_t)it * 256] = v;
    }
}

extern "C" void kernel_launch(void* const* d_in, const int* in_sizes, int n_in,
                              void* d_out, int out_size, void* d_ws, size_t ws_size,
                              hipStream_t stream) {
    const float* h    = (const float*)d_in[0];  // (2, 512, 256) fp32
    const float* W    = (const float*)d_in[1];  // (128, 512)    fp32
    const float* bias = (const float*)d_in[2];  // (128,)        fp32

    float* P1  = (float*)d_ws;                  // 1024 x 128 fp32 = 512 KB
    float* P2b = P1 + (size_t)BLROWS * PDIM;    // 1024 x 128 fp32 = 512 KB

    pair_proj<<<dim3(BLROWS / ROWS), dim3(256), 0, stream>>>(h, W, bias, P1, P2b);

    dim3 g2(BLROWS, 2);
    bcast_add<<<g2, dim3(256), 0, stream>>>((const float4*)P1, (const float4*)P2b,
                                            (float4*)d_out);
}